// Round 4
// baseline (441.093 us; speedup 1.0000x reference)
//
#include <hip/hip_runtime.h>
#include <stdint.h>

#define N_NODES   50000
#define K_DIM     128
#define OUT_DIM   32
#define N_EDGES   1600000
#define NPB       64                         // nodes per bucket (pow2)
#define NBKT      782                        // ceil(50000/64)
#define FITEMS    16                         // edges per thread in hist/fill
#define FBLOCKS   ((N_EDGES + 256*FITEMS - 1) / (256*FITEMS))   // 391

// -------- h = x @ W : [50000,128] x [128,32] -> [50000,32] --------
__global__ __launch_bounds__(256) void gemm_kernel(const float* __restrict__ x,
                                                   const float* __restrict__ w,
                                                   float* __restrict__ h) {
    __shared__ float wlds[K_DIM * OUT_DIM];
    const int t = threadIdx.x;
    #pragma unroll
    for (int i = 0; i < (K_DIM * OUT_DIM) / 256; ++i)
        wlds[i * 256 + t] = w[i * 256 + t];
    __syncthreads();

    const int row = blockIdx.x * 8 + (t >> 5);
    const int col = t & 31;
    if (row >= N_NODES) return;

    const float4* x4 = reinterpret_cast<const float4*>(x + (size_t)row * K_DIM);
    float acc = 0.f;
    #pragma unroll
    for (int k4 = 0; k4 < K_DIM / 4; ++k4) {
        float4 xv = x4[k4];
        const int k = k4 * 4;
        acc += xv.x * wlds[(k + 0) * OUT_DIM + col];
        acc += xv.y * wlds[(k + 1) * OUT_DIM + col];
        acc += xv.z * wlds[(k + 2) * OUT_DIM + col];
        acc += xv.w * wlds[(k + 3) * OUT_DIM + col];
    }
    h[(size_t)row * OUT_DIM + col] = acc;
}

// -------- bucket histogram (LDS-aggregated) --------
__global__ __launch_bounds__(256) void bucket_hist(const int* __restrict__ edst,
                                                   int* __restrict__ counts) {
    __shared__ int cnt[NBKT];
    const int t = threadIdx.x;
    for (int i = t; i < NBKT; i += 256) cnt[i] = 0;
    __syncthreads();
    const int base = blockIdx.x * 256 * FITEMS;
    #pragma unroll
    for (int k = 0; k < FITEMS; ++k) {
        const int e = base + k * 256 + t;
        if (e < N_EDGES) atomicAdd(&cnt[edst[e] >> 6], 1);
    }
    __syncthreads();
    for (int i = t; i < NBKT; i += 256) {
        const int c = cnt[i];
        if (c) atomicAdd(&counts[i], c);
    }
}

// -------- parallel exclusive scan of 782 bucket counts (one block) --------
__global__ __launch_bounds__(1024) void bucket_scan(const int* __restrict__ counts,
                                                    int* __restrict__ bases,
                                                    int* __restrict__ cursor) {
    __shared__ int s[1024];
    const int t = threadIdx.x;
    const int v = (t < NBKT) ? counts[t] : 0;
    s[t] = v;
    __syncthreads();
    #pragma unroll
    for (int d = 1; d < 1024; d <<= 1) {
        int xv = 0;
        if (t >= d) xv = s[t - d];
        __syncthreads();
        if (t >= d) s[t] += xv;
        __syncthreads();
    }
    if (t < NBKT) {
        const int excl = s[t] - v;
        bases[t]  = excl;
        cursor[t] = excl;
    }
}

// -------- fill: bucket-grouped (w,dst,src) pairs, register-held items --------
__global__ __launch_bounds__(256) void bucket_fill(const int*   __restrict__ esrc,
                                                   const int*   __restrict__ edst,
                                                   const float* __restrict__ ew,
                                                   int*         __restrict__ cursor,
                                                   uint64_t*    __restrict__ pairs) {
    __shared__ int cnt[NBKT];
    __shared__ int wbase[NBKT];
    const int t = threadIdx.x;
    for (int i = t; i < NBKT; i += 256) cnt[i] = 0;
    __syncthreads();

    uint32_t lo[FITEMS], hi[FITEMS];
    const int base = blockIdx.x * 256 * FITEMS;
    #pragma unroll
    for (int k = 0; k < FITEMS; ++k) {
        const int e = base + k * 256 + t;
        if (e < N_EDGES) {
            const uint32_t s = (uint32_t)esrc[e];
            const uint32_t d = (uint32_t)edst[e];
            lo[k] = (d << 16) | s;            // dst:16 | src:16 (both < 65536)
            hi[k] = __float_as_uint(ew[e]);
            atomicAdd(&cnt[d >> 6], 1);
        } else {
            lo[k] = 0xffffffffu;              // invalid marker (never a real pair)
        }
    }
    __syncthreads();
    for (int i = t; i < NBKT; i += 256) {
        const int c = cnt[i];
        if (c) wbase[i] = atomicAdd(&cursor[i], c);
    }
    __syncthreads();
    for (int i = t; i < NBKT; i += 256) cnt[i] = 0;   // reuse as running rank
    __syncthreads();
    #pragma unroll
    for (int k = 0; k < FITEMS; ++k) {
        if (lo[k] != 0xffffffffu) {
            const int b = (int)(lo[k] >> 22);          // dst >> 6
            const int r = atomicAdd(&cnt[b], 1);
            pairs[(size_t)wbase[b] + r] = ((uint64_t)hi[k] << 32) | lo[k];
        }
    }
}

// -------- pull v2: 1024 thr, 32 groups, coalesced pair loads + shfl bcast ----
__global__ __launch_bounds__(1024) void bucket_pull(const int*      __restrict__ bases,
                                                    const int*      __restrict__ counts,
                                                    const uint64_t* __restrict__ pairs,
                                                    const float*    __restrict__ h,
                                                    float*          __restrict__ out) {
    __shared__ float acc[NPB * OUT_DIM];     // 8 KB
    const int t = threadIdx.x;
    #pragma unroll
    for (int i = 0; i < (NPB * OUT_DIM) / 1024; ++i) acc[i * 1024 + t] = 0.f;
    __syncthreads();

    const int b    = blockIdx.x;
    const int beg  = bases[b];
    const int cnt  = counts[b];
    const int g    = t >> 5;                 // 32 groups of 32 lanes
    const int lane = t & 31;                 // = output column

    for (int c = g; c * 32 < cnt; c += 32) {
        const int base = beg + c * 32;
        const int m    = min(32, cnt - c * 32);
        uint64_t p = 0;
        if (lane < m) p = pairs[base + lane];    // coalesced 256 B per group

        if (m == 32) {
            #pragma unroll 8
            for (int l = 0; l < 32; ++l) {
                const uint64_t pe = __shfl(p, l, 32);
                const uint32_t lo = (uint32_t)pe;
                const float  wgt = __uint_as_float((uint32_t)(pe >> 32));
                const float  v   = wgt * h[(size_t)(lo & 0xffffu) * OUT_DIM + lane];
                unsafeAtomicAdd(&acc[(((lo >> 16) & (NPB - 1)) << 5) | lane], v);
            }
        } else {
            for (int l = 0; l < m; ++l) {
                const uint64_t pe = __shfl(p, l, 32);
                const uint32_t lo = (uint32_t)pe;
                const float  wgt = __uint_as_float((uint32_t)(pe >> 32));
                const float  v   = wgt * h[(size_t)(lo & 0xffffu) * OUT_DIM + lane];
                unsafeAtomicAdd(&acc[(((lo >> 16) & (NPB - 1)) << 5) | lane], v);
            }
        }
    }
    __syncthreads();

    // coalesced float4 write-out (covers all rows -> no d_out memset needed)
    if (t < (NPB * OUT_DIM) / 4) {           // 512 float4 per bucket
        const long long idx4 = (long long)b * ((NPB * OUT_DIM) / 4) + t;
        if (idx4 < (long long)N_NODES * OUT_DIM / 4)
            reinterpret_cast<float4*>(out)[idx4] =
                reinterpret_cast<const float4*>(acc)[t];
    }
}

// -------- fallback scatter (R1 path) if workspace too small --------
__global__ __launch_bounds__(256) void scatter_kernel(const int*   __restrict__ esrc,
                                                      const int*   __restrict__ edst,
                                                      const float* __restrict__ ew,
                                                      const float* __restrict__ h,
                                                      float*       out) {
    const long long gid = (long long)blockIdx.x * blockDim.x + threadIdx.x;
    const int e   = (int)(gid >> 5);
    const int col = (int)(gid & 31);
    if (e >= N_EDGES) return;
    atomicAdd(out + (size_t)edst[e] * OUT_DIM + col,
              ew[e] * h[(size_t)esrc[e] * OUT_DIM + col]);
}

extern "C" void kernel_launch(void* const* d_in, const int* in_sizes, int n_in,
                              void* d_out, int out_size, void* d_ws, size_t ws_size,
                              hipStream_t stream) {
    const float* x    = (const float*)d_in[0];
    const float* w    = (const float*)d_in[1];
    const int*   esrc = (const int*)d_in[2];
    const int*   edst = (const int*)d_in[3];
    const float* ew   = (const float*)d_in[4];
    float*       out  = (float*)d_out;

    const size_t PAIRS_B = (size_t)N_EDGES * 8;            // 12.8 MB
    const size_t H_B     = (size_t)N_NODES * OUT_DIM * 4;  //  6.4 MB
    const size_t CNT_B   = (size_t)NBKT * 4;               //  3128 B
    const size_t REQ     = PAIRS_B + H_B + 3 * CNT_B + 256;

    if (ws_size >= REQ) {
        uint64_t* pairs  = (uint64_t*)d_ws;
        float*    h      = (float*)((char*)d_ws + PAIRS_B);
        int*      counts = (int*)((char*)d_ws + PAIRS_B + H_B);
        int*      bases  = counts + NBKT;
        int*      cursor = bases + NBKT;

        gemm_kernel<<<(N_NODES + 7) / 8, 256, 0, stream>>>(x, w, h);

        hipMemsetAsync(counts, 0, CNT_B, stream);
        bucket_hist<<<FBLOCKS, 256, 0, stream>>>(edst, counts);
        bucket_scan<<<1, 1024, 0, stream>>>(counts, bases, cursor);
        bucket_fill<<<FBLOCKS, 256, 0, stream>>>(esrc, edst, ew, cursor, pairs);
        bucket_pull<<<NBKT, 1024, 0, stream>>>(bases, counts, pairs, h, out);
    } else {
        float* h = (float*)d_ws;
        hipMemsetAsync(d_out, 0, (size_t)out_size * sizeof(float), stream);
        gemm_kernel<<<(N_NODES + 7) / 8, 256, 0, stream>>>(x, w, h);
        const long long total = (long long)N_EDGES * OUT_DIM;
        scatter_kernel<<<(int)((total + 255) / 256), 256, 0, stream>>>(esrc, edst, ew, h, out);
    }
}

// Round 5
// 439.769 us; speedup vs baseline: 1.0030x; 1.0030x over previous
//
#include <hip/hip_runtime.h>
#include <stdint.h>

#define N_NODES   50000
#define K_DIM     128
#define OUT_DIM   32
#define N_EDGES   1600000
#define NPB       64                         // nodes per bucket (pow2)
#define NBKT      782                        // ceil(50000/64)
#define FITEMS    16                         // edges per thread in hist/fill
#define FBLOCKS   ((N_EDGES + 256*FITEMS - 1) / (256*FITEMS))   // 391

// -------- h = x @ W : [50000,128] x [128,32] -> [50000,32] --------
__global__ __launch_bounds__(256) void gemm_kernel(const float* __restrict__ x,
                                                   const float* __restrict__ w,
                                                   float* __restrict__ h) {
    __shared__ float wlds[K_DIM * OUT_DIM];
    const int t = threadIdx.x;
    #pragma unroll
    for (int i = 0; i < (K_DIM * OUT_DIM) / 256; ++i)
        wlds[i * 256 + t] = w[i * 256 + t];
    __syncthreads();

    const int row = blockIdx.x * 8 + (t >> 5);
    const int col = t & 31;
    if (row >= N_NODES) return;

    const float4* x4 = reinterpret_cast<const float4*>(x + (size_t)row * K_DIM);
    float acc = 0.f;
    #pragma unroll
    for (int k4 = 0; k4 < K_DIM / 4; ++k4) {
        float4 xv = x4[k4];
        const int k = k4 * 4;
        acc += xv.x * wlds[(k + 0) * OUT_DIM + col];
        acc += xv.y * wlds[(k + 1) * OUT_DIM + col];
        acc += xv.z * wlds[(k + 2) * OUT_DIM + col];
        acc += xv.w * wlds[(k + 3) * OUT_DIM + col];
    }
    h[(size_t)row * OUT_DIM + col] = acc;
}

// -------- bucket histogram (LDS-aggregated) --------
__global__ __launch_bounds__(256) void bucket_hist(const int* __restrict__ edst,
                                                   int* __restrict__ counts) {
    __shared__ int cnt[NBKT];
    const int t = threadIdx.x;
    for (int i = t; i < NBKT; i += 256) cnt[i] = 0;
    __syncthreads();
    const int base = blockIdx.x * 256 * FITEMS;
    #pragma unroll
    for (int k = 0; k < FITEMS; ++k) {
        const int e = base + k * 256 + t;
        if (e < N_EDGES) atomicAdd(&cnt[edst[e] >> 6], 1);
    }
    __syncthreads();
    for (int i = t; i < NBKT; i += 256) {
        const int c = cnt[i];
        if (c) atomicAdd(&counts[i], c);
    }
}

// -------- parallel exclusive scan of 782 bucket counts (one block) --------
__global__ __launch_bounds__(1024) void bucket_scan(const int* __restrict__ counts,
                                                    int* __restrict__ bases,
                                                    int* __restrict__ cursor) {
    __shared__ int s[1024];
    const int t = threadIdx.x;
    const int v = (t < NBKT) ? counts[t] : 0;
    s[t] = v;
    __syncthreads();
    #pragma unroll
    for (int d = 1; d < 1024; d <<= 1) {
        int xv = 0;
        if (t >= d) xv = s[t - d];
        __syncthreads();
        if (t >= d) s[t] += xv;
        __syncthreads();
    }
    if (t < NBKT) {
        const int excl = s[t] - v;
        bases[t]  = excl;
        cursor[t] = excl;
    }
}

// -------- fill: bucket-grouped (w,dst,src) pairs, register-held items --------
__global__ __launch_bounds__(256) void bucket_fill(const int*   __restrict__ esrc,
                                                   const int*   __restrict__ edst,
                                                   const float* __restrict__ ew,
                                                   int*         __restrict__ cursor,
                                                   uint64_t*    __restrict__ pairs) {
    __shared__ int cnt[NBKT];
    __shared__ int wbase[NBKT];
    const int t = threadIdx.x;
    for (int i = t; i < NBKT; i += 256) cnt[i] = 0;
    __syncthreads();

    uint32_t lo[FITEMS], hi[FITEMS];
    const int base = blockIdx.x * 256 * FITEMS;
    #pragma unroll
    for (int k = 0; k < FITEMS; ++k) {
        const int e = base + k * 256 + t;
        if (e < N_EDGES) {
            const uint32_t s = (uint32_t)esrc[e];
            const uint32_t d = (uint32_t)edst[e];
            lo[k] = (d << 16) | s;            // dst:16 | src:16 (both < 65536)
            hi[k] = __float_as_uint(ew[e]);
            atomicAdd(&cnt[d >> 6], 1);
        } else {
            lo[k] = 0xffffffffu;              // invalid marker (never a real pair)
        }
    }
    __syncthreads();
    for (int i = t; i < NBKT; i += 256) {
        const int c = cnt[i];
        if (c) wbase[i] = atomicAdd(&cursor[i], c);
    }
    __syncthreads();
    for (int i = t; i < NBKT; i += 256) cnt[i] = 0;   // reuse as running rank
    __syncthreads();
    #pragma unroll
    for (int k = 0; k < FITEMS; ++k) {
        if (lo[k] != 0xffffffffu) {
            const int b = (int)(lo[k] >> 22);          // dst >> 6
            const int r = atomicAdd(&cnt[b], 1);
            pairs[(size_t)wbase[b] + r] = ((uint64_t)hi[k] << 32) | lo[k];
        }
    }
}

// -------- pull v3: native ds_add_f32 LDS accumulation (plain atomicAdd) ------
__global__ __launch_bounds__(1024) void bucket_pull(const int*      __restrict__ bases,
                                                    const int*      __restrict__ counts,
                                                    const uint64_t* __restrict__ pairs,
                                                    const float*    __restrict__ h,
                                                    float*          __restrict__ out) {
    __shared__ float acc[NPB * OUT_DIM];     // 8 KB
    const int t = threadIdx.x;
    #pragma unroll
    for (int i = 0; i < (NPB * OUT_DIM) / 1024; ++i) acc[i * 1024 + t] = 0.f;
    __syncthreads();

    const int b    = blockIdx.x;
    const int beg  = bases[b];
    const int cnt  = counts[b];
    const int g    = t >> 5;                 // 32 groups of 32 lanes
    const int lane = t & 31;                 // = output column

    for (int c = g; c * 32 < cnt; c += 32) {
        const int base = beg + c * 32;
        const int m    = min(32, cnt - c * 32);
        uint64_t p = 0;
        if (lane < m) p = pairs[base + lane];    // coalesced 256 B per group

        if (m == 32) {
            #pragma unroll 8
            for (int l = 0; l < 32; ++l) {
                const uint64_t pe = __shfl(p, l, 32);
                const uint32_t lo = (uint32_t)pe;
                const float  wgt = __uint_as_float((uint32_t)(pe >> 32));
                const float  v   = wgt * h[(size_t)(lo & 0xffffu) * OUT_DIM + lane];
                atomicAdd(&acc[(((lo >> 16) & (NPB - 1)) << 5) | lane], v);  // ds_add_f32
            }
        } else {
            for (int l = 0; l < m; ++l) {
                const uint64_t pe = __shfl(p, l, 32);
                const uint32_t lo = (uint32_t)pe;
                const float  wgt = __uint_as_float((uint32_t)(pe >> 32));
                const float  v   = wgt * h[(size_t)(lo & 0xffffu) * OUT_DIM + lane];
                atomicAdd(&acc[(((lo >> 16) & (NPB - 1)) << 5) | lane], v);
            }
        }
    }
    __syncthreads();

    // coalesced float4 write-out (covers all rows -> no d_out memset needed)
    if (t < (NPB * OUT_DIM) / 4) {           // 512 float4 per bucket
        const long long idx4 = (long long)b * ((NPB * OUT_DIM) / 4) + t;
        if (idx4 < (long long)N_NODES * OUT_DIM / 4)
            reinterpret_cast<float4*>(out)[idx4] =
                reinterpret_cast<const float4*>(acc)[t];
    }
}

// -------- fallback scatter (R1 path) if workspace too small --------
__global__ __launch_bounds__(256) void scatter_kernel(const int*   __restrict__ esrc,
                                                      const int*   __restrict__ edst,
                                                      const float* __restrict__ ew,
                                                      const float* __restrict__ h,
                                                      float*       out) {
    const long long gid = (long long)blockIdx.x * blockDim.x + threadIdx.x;
    const int e   = (int)(gid >> 5);
    const int col = (int)(gid & 31);
    if (e >= N_EDGES) return;
    atomicAdd(out + (size_t)edst[e] * OUT_DIM + col,
              ew[e] * h[(size_t)esrc[e] * OUT_DIM + col]);
}

extern "C" void kernel_launch(void* const* d_in, const int* in_sizes, int n_in,
                              void* d_out, int out_size, void* d_ws, size_t ws_size,
                              hipStream_t stream) {
    const float* x    = (const float*)d_in[0];
    const float* w    = (const float*)d_in[1];
    const int*   esrc = (const int*)d_in[2];
    const int*   edst = (const int*)d_in[3];
    const float* ew   = (const float*)d_in[4];
    float*       out  = (float*)d_out;

    const size_t PAIRS_B = (size_t)N_EDGES * 8;            // 12.8 MB
    const size_t H_B     = (size_t)N_NODES * OUT_DIM * 4;  //  6.4 MB
    const size_t CNT_B   = (size_t)NBKT * 4;               //  3128 B
    const size_t REQ     = PAIRS_B + H_B + 3 * CNT_B + 256;

    if (ws_size >= REQ) {
        uint64_t* pairs  = (uint64_t*)d_ws;
        float*    h      = (float*)((char*)d_ws + PAIRS_B);
        int*      counts = (int*)((char*)d_ws + PAIRS_B + H_B);
        int*      bases  = counts + NBKT;
        int*      cursor = bases + NBKT;

        gemm_kernel<<<(N_NODES + 7) / 8, 256, 0, stream>>>(x, w, h);

        hipMemsetAsync(counts, 0, CNT_B, stream);
        bucket_hist<<<FBLOCKS, 256, 0, stream>>>(edst, counts);
        bucket_scan<<<1, 1024, 0, stream>>>(counts, bases, cursor);
        bucket_fill<<<FBLOCKS, 256, 0, stream>>>(esrc, edst, ew, cursor, pairs);
        bucket_pull<<<NBKT, 1024, 0, stream>>>(bases, counts, pairs, h, out);
    } else {
        float* h = (float*)d_ws;
        hipMemsetAsync(d_out, 0, (size_t)out_size * sizeof(float), stream);
        gemm_kernel<<<(N_NODES + 7) / 8, 256, 0, stream>>>(x, w, h);
        const long long total = (long long)N_EDGES * OUT_DIM;
        scatter_kernel<<<(int)((total + 255) / 256), 256, 0, stream>>>(esrc, edst, ew, h, out);
    }
}

// Round 7
// 198.722 us; speedup vs baseline: 2.2196x; 2.2130x over previous
//
#include <hip/hip_runtime.h>
#include <stdint.h>

#define N_NODES   50000
#define K_DIM     128
#define OUT_DIM   32
#define N_EDGES   1600000
#define NPAD      50176                       // 1024 * 49 (scan grid)
#define NBKT      782                         // 64-node buckets
#define CAP       3072                        // max edges per bucket (Poisson(2048))
#define AFIT      32                          // edges per thread in fillA
#define ABLK      ((N_EDGES + 256*AFIT - 1) / (256*AFIT))   // 196

// -------- h = x @ W : [50000,128] x [128,32] -> [50000,32] --------
__global__ __launch_bounds__(256) void gemm_kernel(const float* __restrict__ x,
                                                   const float* __restrict__ w,
                                                   float* __restrict__ h) {
    __shared__ float wlds[K_DIM * OUT_DIM];
    const int t = threadIdx.x;
    #pragma unroll
    for (int i = 0; i < (K_DIM * OUT_DIM) / 256; ++i)
        wlds[i * 256 + t] = w[i * 256 + t];
    __syncthreads();

    const int row = blockIdx.x * 8 + (t >> 5);
    const int col = t & 31;
    if (row >= N_NODES) return;

    const float4* x4 = reinterpret_cast<const float4*>(x + (size_t)row * K_DIM);
    float acc = 0.f;
    #pragma unroll
    for (int k4 = 0; k4 < K_DIM / 4; ++k4) {
        float4 xv = x4[k4];
        const int k = k4 * 4;
        acc += xv.x * wlds[(k + 0) * OUT_DIM + col];
        acc += xv.y * wlds[(k + 1) * OUT_DIM + col];
        acc += xv.z * wlds[(k + 2) * OUT_DIM + col];
        acc += xv.w * wlds[(k + 3) * OUT_DIM + col];
    }
    h[(size_t)row * OUT_DIM + col] = acc;
}

// -------- per-node histogram (1.6M int atomics) --------
__global__ __launch_bounds__(256) void hist_nodes(const int* __restrict__ edst,
                                                  int* __restrict__ counts) {
    const int e = blockIdx.x * 256 + threadIdx.x;
    if (e < N_EDGES) atomicAdd(&counts[edst[e]], 1);
}

// -------- single-block scan: counts -> exclusive offsets (in place) --------
__global__ __launch_bounds__(1024) void scan_nodes(int* __restrict__ offs,     // counts in, offsets out
                                                   int* __restrict__ cursorA) {
    __shared__ int s[1024];
    const int t = threadIdx.x;
    const int base = t * 49;
    int v[49];
    int sum = 0;
    #pragma unroll
    for (int k = 0; k < 49; ++k) { v[k] = offs[base + k]; sum += v[k]; }
    s[t] = sum;
    __syncthreads();
    #pragma unroll
    for (int d = 1; d < 1024; d <<= 1) {
        int xv = (t >= d) ? s[t - d] : 0;
        __syncthreads();
        s[t] += xv;
        __syncthreads();
    }
    int run = s[t] - sum;                     // exclusive block prefix
    #pragma unroll
    for (int k = 0; k < 49; ++k) { const int c = v[k]; offs[base + k] = run; run += c; }
    __syncthreads();
    // coarse-bucket cursors = offsets at bucket starts
    for (int i = t; i < NBKT; i += 1024) cursorA[i] = offs[i << 6];
}

// -------- fillA: scatter edges into 64-node coarse buckets (R3-proven) ------
__global__ __launch_bounds__(256) void fill_coarse(const int*   __restrict__ esrc,
                                                   const int*   __restrict__ edst,
                                                   const float* __restrict__ ew,
                                                   int*         __restrict__ cursorA,
                                                   uint64_t*    __restrict__ pairs) {
    __shared__ int cnt[NBKT];
    __shared__ int wbase[NBKT];
    const int t = threadIdx.x;
    for (int i = t; i < NBKT; i += 256) cnt[i] = 0;
    __syncthreads();

    uint32_t lo[AFIT], hi[AFIT];
    const int base = blockIdx.x * 256 * AFIT;
    #pragma unroll
    for (int k = 0; k < AFIT; ++k) {
        const int e = base + k * 256 + t;
        if (e < N_EDGES) {
            const uint32_t s = (uint32_t)esrc[e];
            const uint32_t d = (uint32_t)edst[e];
            lo[k] = (d << 16) | s;            // dst:16 | src:16
            hi[k] = __float_as_uint(ew[e]);
            atomicAdd(&cnt[d >> 6], 1);
        } else {
            lo[k] = 0xffffffffu;
        }
    }
    __syncthreads();
    for (int i = t; i < NBKT; i += 256) {
        const int c = cnt[i];
        if (c) wbase[i] = atomicAdd(&cursorA[i], c);
    }
    __syncthreads();
    for (int i = t; i < NBKT; i += 256) cnt[i] = 0;   // reuse as rank
    __syncthreads();
    #pragma unroll
    for (int k = 0; k < AFIT; ++k) {
        if (lo[k] != 0xffffffffu) {
            const int b = (int)(lo[k] >> 22);          // dst >> 6
            const int r = atomicAdd(&cnt[b], 1);
            pairs[(size_t)wbase[b] + r] = ((uint64_t)hi[k] << 32) | lo[k];
        }
    }
}

// -------- fillB: in-place per-node sort of each 64-node bucket via LDS ------
__global__ __launch_bounds__(256) void sort_bucket(const int* __restrict__ offs,
                                                   uint64_t*  __restrict__ pairs) {
    __shared__ uint64_t stg[CAP];             // 24 KB
    __shared__ int lcur[64];
    const int b   = blockIdx.x;
    const int t   = threadIdx.x;
    const int beg = offs[b << 6];
    const int end = offs[(b + 1) << 6];       // (781+1)<<6 = 50048 < NPAD
    const int cnt = end - beg;
    if (cnt <= 0 || cnt > CAP) return;        // cnt>CAP: P ~ 0 (Poisson(2048), >20 sigma)

    for (int i = t; i < cnt; i += 256) stg[i] = pairs[beg + i];
    if (t < 64) lcur[t] = 0;
    __syncthreads();
    for (int i = t; i < cnt; i += 256)
        atomicAdd(&lcur[(int)((stg[i] >> 16) & 63)], 1);   // dst & 63 = local node
    __syncthreads();
    if (t == 0) {                             // exclusive scan of 64 counters
        int run = 0;
        for (int i = 0; i < 64; ++i) { const int c = lcur[i]; lcur[i] = run; run += c; }
    }
    __syncthreads();
    for (int i = t; i < cnt; i += 256) {
        const uint64_t p = stg[i];
        const int pos = atomicAdd(&lcur[(int)((p >> 16) & 63)], 1);
        pairs[beg + pos] = p;                 // single-XCD contiguous region
    }
}

// -------- pull: one node per wave64, register accumulation, no LDS/atomics --
__global__ __launch_bounds__(256) void pull_csr(const int*      __restrict__ offs,
                                                const uint64_t* __restrict__ pairs,
                                                const float*    __restrict__ h,
                                                float*          __restrict__ out) {
    const int wv   = (blockIdx.x * 256 + threadIdx.x) >> 6;   // node id
    const int lane = threadIdx.x & 63;
    const int col  = lane & 31;
    const int half = lane >> 5;               // halves process alternate edges
    if (wv >= N_NODES) return;

    const int beg = offs[wv];
    const int end = offs[wv + 1];
    float acc = 0.f;
    int j = beg + half;
    for (; j + 6 < end; j += 8) {             // 4 edges per half in flight
        const uint64_t p0 = pairs[j];
        const uint64_t p1 = pairs[j + 2];
        const uint64_t p2 = pairs[j + 4];
        const uint64_t p3 = pairs[j + 6];
        const float a0 = h[(size_t)(p0 & 0xffffu) * OUT_DIM + col];
        const float a1 = h[(size_t)(p1 & 0xffffu) * OUT_DIM + col];
        const float a2 = h[(size_t)(p2 & 0xffffu) * OUT_DIM + col];
        const float a3 = h[(size_t)(p3 & 0xffffu) * OUT_DIM + col];
        acc += __uint_as_float((uint32_t)(p0 >> 32)) * a0;
        acc += __uint_as_float((uint32_t)(p1 >> 32)) * a1;
        acc += __uint_as_float((uint32_t)(p2 >> 32)) * a2;
        acc += __uint_as_float((uint32_t)(p3 >> 32)) * a3;
    }
    for (; j < end; j += 2) {
        const uint64_t p = pairs[j];
        acc += __uint_as_float((uint32_t)(p >> 32)) * h[(size_t)(p & 0xffffu) * OUT_DIM + col];
    }
    acc += __shfl_xor(acc, 32, 64);           // combine the two halves
    if (half == 0) out[(size_t)wv * OUT_DIM + col] = acc;
}

// -------- fallback: R1 atomic scatter (known 206 us total) --------
__global__ __launch_bounds__(256) void scatter_kernel(const int*   __restrict__ esrc,
                                                      const int*   __restrict__ edst,
                                                      const float* __restrict__ ew,
                                                      const float* __restrict__ h,
                                                      float*       out) {
    const long long gid = (long long)blockIdx.x * blockDim.x + threadIdx.x;
    const int e   = (int)(gid >> 5);
    const int col = (int)(gid & 31);
    if (e >= N_EDGES) return;
    atomicAdd(out + (size_t)edst[e] * OUT_DIM + col,
              ew[e] * h[(size_t)esrc[e] * OUT_DIM + col]);
}

extern "C" void kernel_launch(void* const* d_in, const int* in_sizes, int n_in,
                              void* d_out, int out_size, void* d_ws, size_t ws_size,
                              hipStream_t stream) {
    const float* x    = (const float*)d_in[0];
    const float* w    = (const float*)d_in[1];
    const int*   esrc = (const int*)d_in[2];
    const int*   edst = (const int*)d_in[3];
    const float* ew   = (const float*)d_in[4];
    float*       out  = (float*)d_out;

    const size_t PAIRS_B = (size_t)N_EDGES * 8;            // 12,800,000
    const size_t H_B     = (size_t)N_NODES * OUT_DIM * 4;  //  6,400,000
    const size_t OFF_B   = (size_t)NPAD * 4;               //    200,704
    const size_t CUR_B   = (size_t)NBKT * 4;               //      3,128
    const size_t REQ     = PAIRS_B + H_B + OFF_B + CUR_B;  // 19,403,832

    if (ws_size >= REQ) {
        uint64_t* pairs   = (uint64_t*)d_ws;
        float*    h       = (float*)((char*)d_ws + PAIRS_B);
        int*      offs    = (int*)((char*)d_ws + PAIRS_B + H_B);
        int*      cursorA = offs + NPAD;

        (void)hipMemsetAsync(offs, 0, OFF_B, stream);      // counts = 0
        hist_nodes<<<N_EDGES / 256, 256, 0, stream>>>(edst, offs);
        scan_nodes<<<1, 1024, 0, stream>>>(offs, cursorA);
        gemm_kernel<<<(N_NODES + 7) / 8, 256, 0, stream>>>(x, w, h);
        fill_coarse<<<ABLK, 256, 0, stream>>>(esrc, edst, ew, cursorA, pairs);
        sort_bucket<<<NBKT, 256, 0, stream>>>(offs, pairs);
        pull_csr<<<(N_NODES * 64 + 255) / 256, 256, 0, stream>>>(offs, pairs, h, out);
    } else {
        float* h = (float*)d_ws;
        (void)hipMemsetAsync(d_out, 0, (size_t)out_size * sizeof(float), stream);
        gemm_kernel<<<(N_NODES + 7) / 8, 256, 0, stream>>>(x, w, h);
        const long long total = (long long)N_EDGES * OUT_DIM;
        scatter_kernel<<<(int)((total + 255) / 256), 256, 0, stream>>>(esrc, edst, ew, h, out);
    }
}

// Round 8
// 130.960 us; speedup vs baseline: 3.3682x; 1.5174x over previous
//
#include <hip/hip_runtime.h>
#include <stdint.h>

#define N_NODES   50000
#define K_DIM     128
#define OUT_DIM   32
#define N_EDGES   1600000
#define NPAD      50176                       // per-node offs array (>= 50048+1)
#define NBKT      782                         // 64-node coarse buckets
#define CAP       3072                        // max edges per bucket (Poisson(2048); R7 verified fit)
#define AFIT      32                          // edges per thread in fill
#define ABLK      ((N_EDGES + 256*AFIT - 1) / (256*AFIT))   // 196
#define HFIT      16
#define HBLK      ((N_EDGES + 256*HFIT - 1) / (256*HFIT))   // 391

// -------- h = x @ W : [50000,128] x [128,32] -> [50000,32] --------
__global__ __launch_bounds__(256) void gemm_kernel(const float* __restrict__ x,
                                                   const float* __restrict__ w,
                                                   float* __restrict__ h) {
    __shared__ float wlds[K_DIM * OUT_DIM];
    const int t = threadIdx.x;
    #pragma unroll
    for (int i = 0; i < (K_DIM * OUT_DIM) / 256; ++i)
        wlds[i * 256 + t] = w[i * 256 + t];
    __syncthreads();

    const int row = blockIdx.x * 8 + (t >> 5);
    const int col = t & 31;
    if (row >= N_NODES) return;

    const float4* x4 = reinterpret_cast<const float4*>(x + (size_t)row * K_DIM);
    float acc = 0.f;
    #pragma unroll
    for (int k4 = 0; k4 < K_DIM / 4; ++k4) {
        float4 xv = x4[k4];
        const int k = k4 * 4;
        acc += xv.x * wlds[(k + 0) * OUT_DIM + col];
        acc += xv.y * wlds[(k + 1) * OUT_DIM + col];
        acc += xv.z * wlds[(k + 2) * OUT_DIM + col];
        acc += xv.w * wlds[(k + 3) * OUT_DIM + col];
    }
    h[(size_t)row * OUT_DIM + col] = acc;
}

// -------- bucket histogram (LDS-aggregated; 782 counters) --------
__global__ __launch_bounds__(256) void bucket_hist(const int* __restrict__ edst,
                                                   int* __restrict__ counts) {
    __shared__ int cnt[NBKT];
    const int t = threadIdx.x;
    for (int i = t; i < NBKT; i += 256) cnt[i] = 0;
    __syncthreads();
    const int base = blockIdx.x * 256 * HFIT;
    #pragma unroll
    for (int k = 0; k < HFIT; ++k) {
        const int e = base + k * 256 + t;
        if (e < N_EDGES) atomicAdd(&cnt[edst[e] >> 6], 1);
    }
    __syncthreads();
    for (int i = t; i < NBKT; i += 256) {
        const int c = cnt[i];
        if (c) atomicAdd(&counts[i], c);
    }
}

// -------- single-block exclusive scan of 782 bucket counts --------
__global__ __launch_bounds__(1024) void bucket_scan(const int* __restrict__ counts,
                                                    int* __restrict__ bases,
                                                    int* __restrict__ cursorA) {
    __shared__ int s[1024];
    const int t = threadIdx.x;
    const int v = (t < NBKT) ? counts[t] : 0;
    s[t] = v;
    __syncthreads();
    #pragma unroll
    for (int d = 1; d < 1024; d <<= 1) {
        int xv = (t >= d) ? s[t - d] : 0;
        __syncthreads();
        s[t] += xv;
        __syncthreads();
    }
    if (t < NBKT) {
        const int excl = s[t] - v;
        bases[t]   = excl;
        cursorA[t] = excl;
    }
}

// -------- fill: scatter edges into 64-node coarse buckets --------
__global__ __launch_bounds__(256) void fill_coarse(const int*   __restrict__ esrc,
                                                   const int*   __restrict__ edst,
                                                   const float* __restrict__ ew,
                                                   int*         __restrict__ cursorA,
                                                   uint64_t*    __restrict__ pairs) {
    __shared__ int cnt[NBKT];
    __shared__ int wbase[NBKT];
    const int t = threadIdx.x;
    for (int i = t; i < NBKT; i += 256) cnt[i] = 0;
    __syncthreads();

    uint32_t lo[AFIT], hi[AFIT];
    const int base = blockIdx.x * 256 * AFIT;
    #pragma unroll
    for (int k = 0; k < AFIT; ++k) {
        const int e = base + k * 256 + t;
        if (e < N_EDGES) {
            const uint32_t s = (uint32_t)esrc[e];
            const uint32_t d = (uint32_t)edst[e];
            lo[k] = (d << 16) | s;            // dst:16 | src:16
            hi[k] = __float_as_uint(ew[e]);
            atomicAdd(&cnt[d >> 6], 1);
        } else {
            lo[k] = 0xffffffffu;
        }
    }
    __syncthreads();
    for (int i = t; i < NBKT; i += 256) {
        const int c = cnt[i];
        if (c) wbase[i] = atomicAdd(&cursorA[i], c);
    }
    __syncthreads();
    for (int i = t; i < NBKT; i += 256) cnt[i] = 0;   // reuse as rank
    __syncthreads();
    #pragma unroll
    for (int k = 0; k < AFIT; ++k) {
        if (lo[k] != 0xffffffffu) {
            const int b = (int)(lo[k] >> 22);          // dst >> 6
            const int r = atomicAdd(&cnt[b], 1);
            pairs[(size_t)wbase[b] + r] = ((uint64_t)hi[k] << 32) | lo[k];
        }
    }
}

// -------- sort bucket by node (in place) AND emit per-node CSR offsets ------
__global__ __launch_bounds__(256) void sort_bucket(const int* __restrict__ bases,
                                                   const int* __restrict__ counts,
                                                   uint64_t*  __restrict__ pairs,
                                                   int*       __restrict__ offs) {
    __shared__ uint64_t stg[CAP];             // 24 KB
    __shared__ int lcnt[64];
    const int b   = blockIdx.x;
    const int t   = threadIdx.x;
    const int beg = bases[b];
    const int cnt = counts[b];
    const bool ok = (cnt > 0 && cnt <= CAP);

    if (t < 64) lcnt[t] = 0;
    __syncthreads();

    if (ok) {
        for (int i = t; i < cnt; i += 256) stg[i] = pairs[beg + i];
        __syncthreads();
        for (int i = t; i < cnt; i += 256)
            atomicAdd(&lcnt[(int)((stg[i] >> 16) & 63)], 1);
    }
    __syncthreads();
    if (t == 0) {                             // exclusive scan, rebased to beg
        int run = beg;
        for (int i = 0; i < 64; ++i) { const int c = lcnt[i]; lcnt[i] = run; run += c; }
    }
    __syncthreads();
    offs_write:
    if (t < 64) offs[(b << 6) + t] = lcnt[t]; // per-node CSR offsets
    __syncthreads();                          // offs read of lcnt before cursor reuse
    if (ok) {
        for (int i = t; i < cnt; i += 256) {
            const uint64_t p = stg[i];
            const int pos = atomicAdd(&lcnt[(int)((p >> 16) & 63)], 1);
            pairs[pos] = p;
        }
    }
}

// -------- pull: one node per wave64, register accumulation ------------------
__global__ __launch_bounds__(256) void pull_csr(const int*      __restrict__ offs,
                                                const uint64_t* __restrict__ pairs,
                                                const float*    __restrict__ h,
                                                float*          __restrict__ out) {
    const int wv   = (blockIdx.x * 256 + threadIdx.x) >> 6;   // node id
    const int lane = threadIdx.x & 63;
    const int col  = lane & 31;
    const int half = lane >> 5;
    if (wv >= N_NODES) return;

    const int beg = offs[wv];
    const int end = offs[wv + 1];
    float acc = 0.f;
    int j = beg + half;
    for (; j + 6 < end; j += 8) {
        const uint64_t p0 = pairs[j];
        const uint64_t p1 = pairs[j + 2];
        const uint64_t p2 = pairs[j + 4];
        const uint64_t p3 = pairs[j + 6];
        const float a0 = h[(size_t)(p0 & 0xffffu) * OUT_DIM + col];
        const float a1 = h[(size_t)(p1 & 0xffffu) * OUT_DIM + col];
        const float a2 = h[(size_t)(p2 & 0xffffu) * OUT_DIM + col];
        const float a3 = h[(size_t)(p3 & 0xffffu) * OUT_DIM + col];
        acc += __uint_as_float((uint32_t)(p0 >> 32)) * a0;
        acc += __uint_as_float((uint32_t)(p1 >> 32)) * a1;
        acc += __uint_as_float((uint32_t)(p2 >> 32)) * a2;
        acc += __uint_as_float((uint32_t)(p3 >> 32)) * a3;
    }
    for (; j < end; j += 2) {
        const uint64_t p = pairs[j];
        acc += __uint_as_float((uint32_t)(p >> 32)) * h[(size_t)(p & 0xffffu) * OUT_DIM + col];
    }
    acc += __shfl_xor(acc, 32, 64);
    if (half == 0) out[(size_t)wv * OUT_DIM + col] = acc;
}

// -------- fallback: R1 atomic scatter --------
__global__ __launch_bounds__(256) void scatter_kernel(const int*   __restrict__ esrc,
                                                      const int*   __restrict__ edst,
                                                      const float* __restrict__ ew,
                                                      const float* __restrict__ h,
                                                      float*       out) {
    const long long gid = (long long)blockIdx.x * blockDim.x + threadIdx.x;
    const int e   = (int)(gid >> 5);
    const int col = (int)(gid & 31);
    if (e >= N_EDGES) return;
    atomicAdd(out + (size_t)edst[e] * OUT_DIM + col,
              ew[e] * h[(size_t)esrc[e] * OUT_DIM + col]);
}

extern "C" void kernel_launch(void* const* d_in, const int* in_sizes, int n_in,
                              void* d_out, int out_size, void* d_ws, size_t ws_size,
                              hipStream_t stream) {
    const float* x    = (const float*)d_in[0];
    const float* w    = (const float*)d_in[1];
    const int*   esrc = (const int*)d_in[2];
    const int*   edst = (const int*)d_in[3];
    const float* ew   = (const float*)d_in[4];
    float*       out  = (float*)d_out;

    const size_t PAIRS_B = (size_t)N_EDGES * 8;            // 12,800,000
    const size_t H_B     = (size_t)N_NODES * OUT_DIM * 4;  //  6,400,000
    const size_t OFF_B   = (size_t)NPAD * 4;               //    200,704
    const size_t BKT_B   = (size_t)NBKT * 4;               //      3,128
    const size_t REQ     = PAIRS_B + H_B + OFF_B + 3 * BKT_B;

    if (ws_size >= REQ) {
        uint64_t* pairs   = (uint64_t*)d_ws;
        float*    h       = (float*)((char*)d_ws + PAIRS_B);
        int*      offs    = (int*)((char*)d_ws + PAIRS_B + H_B);
        int*      counts  = offs + NPAD;
        int*      bases   = counts + NBKT;
        int*      cursorA = bases + NBKT;

        gemm_kernel<<<(N_NODES + 7) / 8, 256, 0, stream>>>(x, w, h);
        (void)hipMemsetAsync(counts, 0, BKT_B, stream);
        bucket_hist<<<HBLK, 256, 0, stream>>>(edst, counts);
        bucket_scan<<<1, 1024, 0, stream>>>(counts, bases, cursorA);
        fill_coarse<<<ABLK, 256, 0, stream>>>(esrc, edst, ew, cursorA, pairs);
        sort_bucket<<<NBKT, 256, 0, stream>>>(bases, counts, pairs, offs);
        pull_csr<<<(N_NODES * 64 + 255) / 256, 256, 0, stream>>>(offs, pairs, h, out);
    } else {
        float* h = (float*)d_ws;
        (void)hipMemsetAsync(d_out, 0, (size_t)out_size * sizeof(float), stream);
        gemm_kernel<<<(N_NODES + 7) / 8, 256, 0, stream>>>(x, w, h);
        const long long total = (long long)N_EDGES * OUT_DIM;
        scatter_kernel<<<(int)((total + 255) / 256), 256, 0, stream>>>(esrc, edst, ew, h, out);
    }
}

// Round 9
// 106.467 us; speedup vs baseline: 4.1430x; 1.2301x over previous
//
#include <hip/hip_runtime.h>
#include <hip/hip_bf16.h>
#include <stdint.h>

#define N_NODES   50000
#define K_DIM     128
#define OUT_DIM   32
#define N_EDGES   1600000
#define NBKT      782                         // 64-node coarse buckets
#define CAP       3072                        // max edges/bucket (Poisson(2048), >20 sigma)
#define AFIT      16                          // edges per thread in fill
#define ABLK      ((N_EDGES + 256*AFIT - 1) / (256*AFIT))   // 391
#define HFIT      16
#define HBLK      ((N_EDGES + 256*HFIT - 1) / (256*HFIT))   // 391

// -------- h = x @ W -> bf16 [50000,32] (fits 4 MB per-XCD L2) --------
__global__ __launch_bounds__(256) void gemm_kernel(const float* __restrict__ x,
                                                   const float* __restrict__ w,
                                                   __hip_bfloat16* __restrict__ h) {
    __shared__ float wlds[K_DIM * OUT_DIM];
    const int t = threadIdx.x;
    #pragma unroll
    for (int i = 0; i < (K_DIM * OUT_DIM) / 256; ++i)
        wlds[i * 256 + t] = w[i * 256 + t];
    __syncthreads();

    const int row = blockIdx.x * 8 + (t >> 5);
    const int col = t & 31;
    if (row >= N_NODES) return;

    const float4* x4 = reinterpret_cast<const float4*>(x + (size_t)row * K_DIM);
    float acc = 0.f;
    #pragma unroll
    for (int k4 = 0; k4 < K_DIM / 4; ++k4) {
        float4 xv = x4[k4];
        const int k = k4 * 4;
        acc += xv.x * wlds[(k + 0) * OUT_DIM + col];
        acc += xv.y * wlds[(k + 1) * OUT_DIM + col];
        acc += xv.z * wlds[(k + 2) * OUT_DIM + col];
        acc += xv.w * wlds[(k + 3) * OUT_DIM + col];
    }
    h[(size_t)row * OUT_DIM + col] = __float2bfloat16(acc);
}

// -------- bucket histogram (LDS-aggregated; 782 counters) --------
__global__ __launch_bounds__(256) void bucket_hist(const int* __restrict__ edst,
                                                   int* __restrict__ counts) {
    __shared__ int cnt[NBKT];
    const int t = threadIdx.x;
    for (int i = t; i < NBKT; i += 256) cnt[i] = 0;
    __syncthreads();
    const int base = blockIdx.x * 256 * HFIT;
    #pragma unroll
    for (int k = 0; k < HFIT; ++k) {
        const int e = base + k * 256 + t;
        if (e < N_EDGES) atomicAdd(&cnt[edst[e] >> 6], 1);
    }
    __syncthreads();
    for (int i = t; i < NBKT; i += 256) {
        const int c = cnt[i];
        if (c) atomicAdd(&counts[i], c);
    }
}

// -------- single-block exclusive scan of 782 bucket counts --------
__global__ __launch_bounds__(1024) void bucket_scan(const int* __restrict__ counts,
                                                    int* __restrict__ bases,
                                                    int* __restrict__ cursorA) {
    __shared__ int s[1024];
    const int t = threadIdx.x;
    const int v = (t < NBKT) ? counts[t] : 0;
    s[t] = v;
    __syncthreads();
    #pragma unroll
    for (int d = 1; d < 1024; d <<= 1) {
        int xv = (t >= d) ? s[t - d] : 0;
        __syncthreads();
        s[t] += xv;
        __syncthreads();
    }
    if (t < NBKT) {
        const int excl = s[t] - v;
        bases[t]   = excl;
        cursorA[t] = excl;
    }
}

// -------- fill: scatter edges into 64-node coarse buckets --------
__global__ __launch_bounds__(256) void fill_coarse(const int*   __restrict__ esrc,
                                                   const int*   __restrict__ edst,
                                                   const float* __restrict__ ew,
                                                   int*         __restrict__ cursorA,
                                                   uint64_t*    __restrict__ pairs) {
    __shared__ int cnt[NBKT];
    __shared__ int wbase[NBKT];
    const int t = threadIdx.x;
    for (int i = t; i < NBKT; i += 256) cnt[i] = 0;
    __syncthreads();

    uint32_t lo[AFIT], hi[AFIT];
    const int base = blockIdx.x * 256 * AFIT;
    #pragma unroll
    for (int k = 0; k < AFIT; ++k) {
        const int e = base + k * 256 + t;
        if (e < N_EDGES) {
            const uint32_t s = (uint32_t)esrc[e];
            const uint32_t d = (uint32_t)edst[e];
            lo[k] = (d << 16) | s;            // dst:16 | src:16
            hi[k] = __float_as_uint(ew[e]);
            atomicAdd(&cnt[d >> 6], 1);
        } else {
            lo[k] = 0xffffffffu;
        }
    }
    __syncthreads();
    for (int i = t; i < NBKT; i += 256) {
        const int c = cnt[i];
        if (c) wbase[i] = atomicAdd(&cursorA[i], c);
    }
    __syncthreads();
    for (int i = t; i < NBKT; i += 256) cnt[i] = 0;   // reuse as rank
    __syncthreads();
    #pragma unroll
    for (int k = 0; k < AFIT; ++k) {
        if (lo[k] != 0xffffffffu) {
            const int b = (int)(lo[k] >> 22);          // dst >> 6
            const int r = atomicAdd(&cnt[b], 1);
            pairs[(size_t)wbase[b] + r] = ((uint64_t)hi[k] << 32) | lo[k];
        }
    }
}

// -------- fused sort+pull: per bucket, LDS-sort edges then register-pull ----
__global__ __launch_bounds__(512) void sort_pull(const int*      __restrict__ bases,
                                                 const int*      __restrict__ counts,
                                                 const uint64_t* __restrict__ pairs,
                                                 const __hip_bfloat16* __restrict__ h,
                                                 float*          __restrict__ out) {
    __shared__ uint64_t stg[CAP];             // 24 KB
    __shared__ int lcnt[64];
    __shared__ int loff[65];
    const int b    = blockIdx.x;
    const int t    = threadIdx.x;
    const int beg  = bases[b];
    const int cnt  = counts[b];
    const int wv   = t >> 6;                  // 8 waves
    const int lane = t & 63;
    const int col  = lane & 31;
    const int half = lane >> 5;

    if (t < 64) lcnt[t] = 0;
    __syncthreads();

    if (cnt <= CAP) {
        // phase 1: count per local node
        for (int i = t; i < cnt; i += 512)
            atomicAdd(&lcnt[(int)((pairs[beg + i] >> 16) & 63)], 1);
        __syncthreads();
        if (t == 0) {
            int run = 0;
            #pragma unroll
            for (int i = 0; i < 64; ++i) { loff[i] = run; run += lcnt[i]; }
            loff[64] = run;
        }
        __syncthreads();
        if (t < 64) lcnt[t] = loff[t];        // cursor
        __syncthreads();
        // phase 2: sort into LDS (pairs re-read is L2-hot)
        for (int i = t; i < cnt; i += 512) {
            const uint64_t p = pairs[beg + i];
            const int pos = atomicAdd(&lcnt[(int)((p >> 16) & 63)], 1);
            stg[pos] = p;
        }
        __syncthreads();
        // phase 3: pull — wave wv owns local nodes wv*8..wv*8+7
        for (int nl = wv * 8; nl < wv * 8 + 8; ++nl) {
            const int node = (b << 6) + nl;
            if (node >= N_NODES) break;
            const int jb = loff[nl], je = loff[nl + 1];
            float acc = 0.f;
            int j = jb + half;
            for (; j + 6 < je; j += 8) {
                const uint64_t p0 = stg[j];
                const uint64_t p1 = stg[j + 2];
                const uint64_t p2 = stg[j + 4];
                const uint64_t p3 = stg[j + 6];
                const float a0 = __bfloat162float(h[(size_t)(p0 & 0xffffu) * OUT_DIM + col]);
                const float a1 = __bfloat162float(h[(size_t)(p1 & 0xffffu) * OUT_DIM + col]);
                const float a2 = __bfloat162float(h[(size_t)(p2 & 0xffffu) * OUT_DIM + col]);
                const float a3 = __bfloat162float(h[(size_t)(p3 & 0xffffu) * OUT_DIM + col]);
                acc += __uint_as_float((uint32_t)(p0 >> 32)) * a0;
                acc += __uint_as_float((uint32_t)(p1 >> 32)) * a1;
                acc += __uint_as_float((uint32_t)(p2 >> 32)) * a2;
                acc += __uint_as_float((uint32_t)(p3 >> 32)) * a3;
            }
            for (; j < je; j += 2) {
                const uint64_t p = stg[j];
                acc += __uint_as_float((uint32_t)(p >> 32)) *
                       __bfloat162float(h[(size_t)(p & 0xffffu) * OUT_DIM + col]);
            }
            acc += __shfl_xor(acc, 32, 64);
            if (half == 0) out[(size_t)node * OUT_DIM + col] = acc;
        }
    } else {
        // safety path (statistically never taken): predicated scan per node
        for (int nl = wv * 8; nl < wv * 8 + 8; ++nl) {
            const int node = (b << 6) + nl;
            if (node >= N_NODES) break;
            float acc = 0.f;
            for (int j = half; j < cnt; j += 2) {
                const uint64_t p = pairs[beg + j];
                if ((int)((p >> 16) & 63) == nl)
                    acc += __uint_as_float((uint32_t)(p >> 32)) *
                           __bfloat162float(h[(size_t)(p & 0xffffu) * OUT_DIM + col]);
            }
            acc += __shfl_xor(acc, 32, 64);
            if (half == 0) out[(size_t)node * OUT_DIM + col] = acc;
        }
    }
}

// -------- fallback: atomic scatter (bf16 h) --------
__global__ __launch_bounds__(256) void scatter_kernel(const int*   __restrict__ esrc,
                                                      const int*   __restrict__ edst,
                                                      const float* __restrict__ ew,
                                                      const __hip_bfloat16* __restrict__ h,
                                                      float*       out) {
    const long long gid = (long long)blockIdx.x * blockDim.x + threadIdx.x;
    const int e   = (int)(gid >> 5);
    const int col = (int)(gid & 31);
    if (e >= N_EDGES) return;
    atomicAdd(out + (size_t)edst[e] * OUT_DIM + col,
              ew[e] * __bfloat162float(h[(size_t)esrc[e] * OUT_DIM + col]));
}

extern "C" void kernel_launch(void* const* d_in, const int* in_sizes, int n_in,
                              void* d_out, int out_size, void* d_ws, size_t ws_size,
                              hipStream_t stream) {
    const float* x    = (const float*)d_in[0];
    const float* w    = (const float*)d_in[1];
    const int*   esrc = (const int*)d_in[2];
    const int*   edst = (const int*)d_in[3];
    const float* ew   = (const float*)d_in[4];
    float*       out  = (float*)d_out;

    const size_t PAIRS_B = (size_t)N_EDGES * 8;            // 12,800,000
    const size_t H_B     = (size_t)N_NODES * OUT_DIM * 2;  //  3,200,000 (bf16)
    const size_t BKT_B   = (size_t)NBKT * 4;               //      3,128
    const size_t REQ     = PAIRS_B + H_B + 3 * BKT_B;

    uint64_t*        pairs   = (uint64_t*)d_ws;
    __hip_bfloat16*  h       = (__hip_bfloat16*)((char*)d_ws + PAIRS_B);
    int*             counts  = (int*)((char*)d_ws + PAIRS_B + H_B);
    int*             bases   = counts + NBKT;
    int*             cursorA = bases + NBKT;

    if (ws_size >= REQ) {
        gemm_kernel<<<(N_NODES + 7) / 8, 256, 0, stream>>>(x, w, h);
        (void)hipMemsetAsync(counts, 0, BKT_B, stream);
        bucket_hist<<<HBLK, 256, 0, stream>>>(edst, counts);
        bucket_scan<<<1, 1024, 0, stream>>>(counts, bases, cursorA);
        fill_coarse<<<ABLK, 256, 0, stream>>>(esrc, edst, ew, cursorA, pairs);
        sort_pull<<<NBKT, 512, 0, stream>>>(bases, counts, pairs, h, out);
    } else {
        __hip_bfloat16* hf = (__hip_bfloat16*)d_ws;
        (void)hipMemsetAsync(d_out, 0, (size_t)out_size * sizeof(float), stream);
        gemm_kernel<<<(N_NODES + 7) / 8, 256, 0, stream>>>(x, w, hf);
        const long long total = (long long)N_EDGES * OUT_DIM;
        scatter_kernel<<<(int)((total + 255) / 256), 256, 0, stream>>>(esrc, edst, ew, hf, out);
    }
}

// Round 10
// 103.484 us; speedup vs baseline: 4.2624x; 1.0288x over previous
//
#include <hip/hip_runtime.h>
#include <hip/hip_bf16.h>
#include <stdint.h>

#define N_NODES   50000
#define K_DIM     128
#define OUT_DIM   32
#define N_EDGES   1600000
#define NBKT      782                         // 64-node coarse buckets
#define CAP       3072                        // max edges/bucket (Poisson(2048), >20 sigma)
#define AFIT      16                          // edges per thread in fill
#define ABLK      ((N_EDGES + 256*AFIT - 1) / (256*AFIT))   // 391
#define HFIT      16
#define HBLK      ((N_EDGES + 256*HFIT - 1) / (256*HFIT))   // 391

// -------- h = x @ W -> bf16 [50000,32]; block 0 also zeroes bucket counts ----
__global__ __launch_bounds__(256) void gemm_kernel(const float* __restrict__ x,
                                                   const float* __restrict__ w,
                                                   __hip_bfloat16* __restrict__ h,
                                                   int* __restrict__ counts) {
    __shared__ float wlds[K_DIM * OUT_DIM];
    const int t = threadIdx.x;
    // replaces the pathological 42-us hipMemsetAsync(fillBufferAligned) in the graph
    if (blockIdx.x == 0) {
        for (int i = t; i < NBKT; i += 256) counts[i] = 0;
    }
    #pragma unroll
    for (int i = 0; i < (K_DIM * OUT_DIM) / 256; ++i)
        wlds[i * 256 + t] = w[i * 256 + t];
    __syncthreads();

    const int row = blockIdx.x * 8 + (t >> 5);
    const int col = t & 31;
    if (row >= N_NODES) return;

    const float4* x4 = reinterpret_cast<const float4*>(x + (size_t)row * K_DIM);
    float acc = 0.f;
    #pragma unroll
    for (int k4 = 0; k4 < K_DIM / 4; ++k4) {
        float4 xv = x4[k4];
        const int k = k4 * 4;
        acc += xv.x * wlds[(k + 0) * OUT_DIM + col];
        acc += xv.y * wlds[(k + 1) * OUT_DIM + col];
        acc += xv.z * wlds[(k + 2) * OUT_DIM + col];
        acc += xv.w * wlds[(k + 3) * OUT_DIM + col];
    }
    h[(size_t)row * OUT_DIM + col] = __float2bfloat16(acc);
}

// -------- bucket histogram (LDS-aggregated; 782 counters) --------
__global__ __launch_bounds__(256) void bucket_hist(const int* __restrict__ edst,
                                                   int* __restrict__ counts) {
    __shared__ int cnt[NBKT];
    const int t = threadIdx.x;
    for (int i = t; i < NBKT; i += 256) cnt[i] = 0;
    __syncthreads();
    const int base = blockIdx.x * 256 * HFIT;
    #pragma unroll
    for (int k = 0; k < HFIT; ++k) {
        const int e = base + k * 256 + t;
        if (e < N_EDGES) atomicAdd(&cnt[edst[e] >> 6], 1);
    }
    __syncthreads();
    for (int i = t; i < NBKT; i += 256) {
        const int c = cnt[i];
        if (c) atomicAdd(&counts[i], c);
    }
}

// -------- single-block exclusive scan of 782 bucket counts --------
__global__ __launch_bounds__(1024) void bucket_scan(const int* __restrict__ counts,
                                                    int* __restrict__ bases,
                                                    int* __restrict__ cursorA) {
    __shared__ int s[1024];
    const int t = threadIdx.x;
    const int v = (t < NBKT) ? counts[t] : 0;
    s[t] = v;
    __syncthreads();
    #pragma unroll
    for (int d = 1; d < 1024; d <<= 1) {
        int xv = (t >= d) ? s[t - d] : 0;
        __syncthreads();
        s[t] += xv;
        __syncthreads();
    }
    if (t < NBKT) {
        const int excl = s[t] - v;
        bases[t]   = excl;
        cursorA[t] = excl;
    }
}

// -------- fill: scatter edges into 64-node coarse buckets --------
__global__ __launch_bounds__(256) void fill_coarse(const int*   __restrict__ esrc,
                                                   const int*   __restrict__ edst,
                                                   const float* __restrict__ ew,
                                                   int*         __restrict__ cursorA,
                                                   uint64_t*    __restrict__ pairs) {
    __shared__ int cnt[NBKT];
    __shared__ int wbase[NBKT];
    const int t = threadIdx.x;
    for (int i = t; i < NBKT; i += 256) cnt[i] = 0;
    __syncthreads();

    uint32_t lo[AFIT], hi[AFIT];
    const int base = blockIdx.x * 256 * AFIT;
    #pragma unroll
    for (int k = 0; k < AFIT; ++k) {
        const int e = base + k * 256 + t;
        if (e < N_EDGES) {
            const uint32_t s = (uint32_t)esrc[e];
            const uint32_t d = (uint32_t)edst[e];
            lo[k] = (d << 16) | s;            // dst:16 | src:16
            hi[k] = __float_as_uint(ew[e]);
            atomicAdd(&cnt[d >> 6], 1);
        } else {
            lo[k] = 0xffffffffu;
        }
    }
    __syncthreads();
    for (int i = t; i < NBKT; i += 256) {
        const int c = cnt[i];
        if (c) wbase[i] = atomicAdd(&cursorA[i], c);
    }
    __syncthreads();
    for (int i = t; i < NBKT; i += 256) cnt[i] = 0;   // reuse as rank
    __syncthreads();
    #pragma unroll
    for (int k = 0; k < AFIT; ++k) {
        if (lo[k] != 0xffffffffu) {
            const int b = (int)(lo[k] >> 22);          // dst >> 6
            const int r = atomicAdd(&cnt[b], 1);
            pairs[(size_t)wbase[b] + r] = ((uint64_t)hi[k] << 32) | lo[k];
        }
    }
}

// -------- fused sort+pull: per bucket, LDS-sort edges then register-pull ----
__global__ __launch_bounds__(512) void sort_pull(const int*      __restrict__ bases,
                                                 const int*      __restrict__ counts,
                                                 const uint64_t* __restrict__ pairs,
                                                 const __hip_bfloat16* __restrict__ h,
                                                 float*          __restrict__ out) {
    __shared__ uint64_t stg[CAP];             // 24 KB
    __shared__ int lcnt[64];
    __shared__ int loff[65];
    const int b    = blockIdx.x;
    const int t    = threadIdx.x;
    const int beg  = bases[b];
    const int cnt  = counts[b];
    const int wv   = t >> 6;                  // 8 waves
    const int lane = t & 63;
    const int col  = lane & 31;
    const int half = lane >> 5;

    if (t < 64) lcnt[t] = 0;
    __syncthreads();

    if (cnt <= CAP) {
        for (int i = t; i < cnt; i += 512)
            atomicAdd(&lcnt[(int)((pairs[beg + i] >> 16) & 63)], 1);
        __syncthreads();
        if (t == 0) {
            int run = 0;
            #pragma unroll
            for (int i = 0; i < 64; ++i) { loff[i] = run; run += lcnt[i]; }
            loff[64] = run;
        }
        __syncthreads();
        if (t < 64) lcnt[t] = loff[t];        // cursor
        __syncthreads();
        for (int i = t; i < cnt; i += 512) {
            const uint64_t p = pairs[beg + i];
            const int pos = atomicAdd(&lcnt[(int)((p >> 16) & 63)], 1);
            stg[pos] = p;
        }
        __syncthreads();
        for (int nl = wv * 8; nl < wv * 8 + 8; ++nl) {
            const int node = (b << 6) + nl;
            if (node >= N_NODES) break;
            const int jb = loff[nl], je = loff[nl + 1];
            float acc = 0.f;
            int j = jb + half;
            for (; j + 6 < je; j += 8) {
                const uint64_t p0 = stg[j];
                const uint64_t p1 = stg[j + 2];
                const uint64_t p2 = stg[j + 4];
                const uint64_t p3 = stg[j + 6];
                const float a0 = __bfloat162float(h[(size_t)(p0 & 0xffffu) * OUT_DIM + col]);
                const float a1 = __bfloat162float(h[(size_t)(p1 & 0xffffu) * OUT_DIM + col]);
                const float a2 = __bfloat162float(h[(size_t)(p2 & 0xffffu) * OUT_DIM + col]);
                const float a3 = __bfloat162float(h[(size_t)(p3 & 0xffffu) * OUT_DIM + col]);
                acc += __uint_as_float((uint32_t)(p0 >> 32)) * a0;
                acc += __uint_as_float((uint32_t)(p1 >> 32)) * a1;
                acc += __uint_as_float((uint32_t)(p2 >> 32)) * a2;
                acc += __uint_as_float((uint32_t)(p3 >> 32)) * a3;
            }
            for (; j < je; j += 2) {
                const uint64_t p = stg[j];
                acc += __uint_as_float((uint32_t)(p >> 32)) *
                       __bfloat162float(h[(size_t)(p & 0xffffu) * OUT_DIM + col]);
            }
            acc += __shfl_xor(acc, 32, 64);
            if (half == 0) out[(size_t)node * OUT_DIM + col] = acc;
        }
    } else {
        // safety path (statistically never taken): predicated scan per node
        for (int nl = wv * 8; nl < wv * 8 + 8; ++nl) {
            const int node = (b << 6) + nl;
            if (node >= N_NODES) break;
            float acc = 0.f;
            for (int j = half; j < cnt; j += 2) {
                const uint64_t p = pairs[beg + j];
                if ((int)((p >> 16) & 63) == nl)
                    acc += __uint_as_float((uint32_t)(p >> 32)) *
                           __bfloat162float(h[(size_t)(p & 0xffffu) * OUT_DIM + col]);
            }
            acc += __shfl_xor(acc, 32, 64);
            if (half == 0) out[(size_t)node * OUT_DIM + col] = acc;
        }
    }
}

// -------- fallback: atomic scatter (bf16 h) --------
__global__ __launch_bounds__(256) void scatter_kernel(const int*   __restrict__ esrc,
                                                      const int*   __restrict__ edst,
                                                      const float* __restrict__ ew,
                                                      const __hip_bfloat16* __restrict__ h,
                                                      float*       out) {
    const long long gid = (long long)blockIdx.x * blockDim.x + threadIdx.x;
    const int e   = (int)(gid >> 5);
    const int col = (int)(gid & 31);
    if (e >= N_EDGES) return;
    atomicAdd(out + (size_t)edst[e] * OUT_DIM + col,
              ew[e] * __bfloat162float(h[(size_t)esrc[e] * OUT_DIM + col]));
}

extern "C" void kernel_launch(void* const* d_in, const int* in_sizes, int n_in,
                              void* d_out, int out_size, void* d_ws, size_t ws_size,
                              hipStream_t stream) {
    const float* x    = (const float*)d_in[0];
    const float* w    = (const float*)d_in[1];
    const int*   esrc = (const int*)d_in[2];
    const int*   edst = (const int*)d_in[3];
    const float* ew   = (const float*)d_in[4];
    float*       out  = (float*)d_out;

    const size_t PAIRS_B = (size_t)N_EDGES * 8;            // 12,800,000
    const size_t H_B     = (size_t)N_NODES * OUT_DIM * 2;  //  3,200,000 (bf16)
    const size_t BKT_B   = (size_t)NBKT * 4;               //      3,128
    const size_t REQ     = PAIRS_B + H_B + 3 * BKT_B;

    uint64_t*        pairs   = (uint64_t*)d_ws;
    __hip_bfloat16*  h       = (__hip_bfloat16*)((char*)d_ws + PAIRS_B);
    int*             counts  = (int*)((char*)d_ws + PAIRS_B + H_B);
    int*             bases   = counts + NBKT;
    int*             cursorA = bases + NBKT;

    if (ws_size >= REQ) {
        gemm_kernel<<<(N_NODES + 7) / 8, 256, 0, stream>>>(x, w, h, counts);
        bucket_hist<<<HBLK, 256, 0, stream>>>(edst, counts);
        bucket_scan<<<1, 1024, 0, stream>>>(counts, bases, cursorA);
        fill_coarse<<<ABLK, 256, 0, stream>>>(esrc, edst, ew, cursorA, pairs);
        sort_pull<<<NBKT, 512, 0, stream>>>(bases, counts, pairs, h, out);
    } else {
        __hip_bfloat16* hf = (__hip_bfloat16*)d_ws;
        (void)hipMemsetAsync(d_out, 0, (size_t)out_size * sizeof(float), stream);
        gemm_kernel<<<(N_NODES + 7) / 8, 256, 0, stream>>>(x, w, hf, (int*)((char*)d_ws + H_B));
        const long long total = (long long)N_EDGES * OUT_DIM;
        scatter_kernel<<<(int)((total + 255) / 256), 256, 0, stream>>>(esrc, edst, ew, hf, out);
    }
}